// Round 5
// baseline (409.747 us; speedup 1.0000x reference)
//
#include <hip/hip_runtime.h>
#include <hip/hip_bf16.h>
#include <stdint.h>
#include <math.h>

#define TT 128
#define CC 600
#define HH 75

typedef __attribute__((ext_vector_type(8)))  short bh8;
typedef __attribute__((ext_vector_type(16))) float f32x16;
typedef __attribute__((ext_vector_type(4)))  float f32x4;

// ---- LDS layout (bytes), total 73728 -> comfortably 2 blocks/CU ----
// phase 1: XA[2] f32 x-staging @0 (2*16384) [0,32768)
// phase 2+ alias: P @0 (16384), PM @16384 (1024), PS @17408 (1024)
// persistent: Q @32768 (20480), K @53248 (20480)
#define XA_OFF 0
#define P_OFF  0
#define PM_OFF 16384
#define PS_OFF 17408
#define Q_OFF  32768
#define K_OFF  53248
#define LDS_BYTES 73728

// ws layout: wpack @0 (311296B), vT @524288 (512*20480B)
#define VWS_OFF 524288

__device__ __forceinline__ uint32_t f2bf1(float f) {
  uint32_t u = __float_as_uint(f);
  return (u + 0x7FFFu + ((u >> 16) & 1u)) >> 16;   // RNE f32->bf16
}
__device__ __forceinline__ uint32_t packbf(float a, float b) {
  return f2bf1(a) | (f2bf1(b) << 16);
}
__device__ __forceinline__ float bfrt(float f) {   // bf16 round-trip
  return __uint_as_float(f2bf1(f) << 16);
}
// P: 128B-stride rows, XOR-swizzle 16B-slot index by row&7
__device__ __forceinline__ int pswz(int row, int bytein) {
  return row * 128 + (bytein ^ ((row & 7) << 4));
}
// async global(16B) -> LDS, linear per-lane dest
__device__ __forceinline__ void gl_lds16(const float* g, char* l) {
  __builtin_amdgcn_global_load_lds(
      (const __attribute__((address_space(1))) unsigned int*)(const void*)g,
      (__attribute__((address_space(3))) unsigned int*)l, 16, 0, 0);
}

// ---------------- prepass: pack W as per-lane MFMA B-fragments ----------------
// fragment (cs = c*2+ks, n, h5) = 8 bf16 of column n, k = cs*16 + h5*8 + j.
// n = sec*80 + h (0=q,1=k,2=v); zeros for h>=75, n>=240, k>=600.
__global__ void pack_w_kernel(const float* __restrict__ Wq, const float* __restrict__ Wk,
                              const float* __restrict__ Wv, uint16_t* __restrict__ wpack) {
  const int cs  = blockIdx.x;      // 0..37
  const int tid = threadIdx.x;     // 0..511
  const int n   = tid >> 1;
  const int h5  = tid & 1;
  const int sec = n / 80;
  const int h   = n - sec * 80;
  const float* W = (sec == 0) ? Wq : (sec == 1) ? Wk : (sec == 2) ? Wv : nullptr;
  const bool valid = (W != nullptr) && (h < HH);
  const int k0 = cs * 16 + h5 * 8;
  uint32_t u[4] = {0u, 0u, 0u, 0u};
  if (valid) {
#pragma unroll
    for (int j = 0; j < 8; ++j) {
      const int k = k0 + j;
      float v = (k < CC) ? W[k * HH + h] : 0.f;
      u[j >> 1] |= f2bf1(v) << ((j & 1) * 16);
    }
  }
  ((uint4*)wpack)[cs * 512 + n * 2 + h5] = make_uint4(u[0], u[1], u[2], u[3]);
}

// ---------------- main: fused qkv-projection + causal attention, one WG per batch ----------------
__global__ __launch_bounds__(512, 4) void head_kernel(
    const float* __restrict__ x, const uint16_t* __restrict__ wpack,
    uint16_t* __restrict__ vws, float* __restrict__ out)
{
  __shared__ char smem[LDS_BYTES];
  const int tid  = threadIdx.x;
  const int b    = blockIdx.x;
  const int lane = tid & 63;
  const int wv   = tid >> 6;      // wave 0..7
  const int l31  = lane & 31;
  const int h5   = lane >> 5;

  //========================= phase 1: [128x600]@[600x240] -> q,k,v =========================
  const int m0 = (wv >> 2) * 64;  // wave tile: 64x64
  const int n0 = (wv & 3) * 64;

  f32x16 acc[2][2];
#pragma unroll
  for (int mi = 0; mi < 2; ++mi)
#pragma unroll
    for (int ni = 0; ni < 2; ++ni)
#pragma unroll
      for (int r = 0; r < 16; ++r) acc[mi][ni][r] = 0.f;

  // DMA staging geometry: LDS tile = f32 x[t][32] (128B rows), swizzled slots.
  // thread tid stages LDS bytes tid*16 (t=tid>>3) and 8192+tid*16 (t=64+tid>>3);
  // source column pre-swizzled so that swizzled reads see the right data.
  const int sxt  = tid >> 3;                         // 0..63
  const int sxs  = (tid & 7) ^ (sxt & 7);            // pre-swizzled 16B slot
  const float* xrow0 = x + (size_t)b * (TT * CC) + (size_t)sxt * CC;
  const float* xrow1 = xrow0 + (size_t)64 * CC;
  char* const ld0 = smem + XA_OFF + tid * 16;        // = wave base + lane*16
  const bh8* wfp = (const bh8*)wpack;                // 16B W fragments in L2
  const int woff = (n0 + l31) * 2 + h5;
  uint16_t* vtb = vws + (size_t)b * (80 * 128);      // V^T [h][t] bf16 in ws

  { // prologue: DMA chunk 0 into buffer 0
    const int kc = sxs * 4;
    gl_lds16(xrow0 + kc, ld0);
    gl_lds16(xrow1 + kc, ld0 + 8192);
    __syncthreads();
  }

  for (int c = 0; c < 19; ++c) {
    const int buf = c & 1;
    if (c + 1 < 19) {  // DMA next chunk into the other buffer (fire-and-forget)
      int kc = (c + 1) * 32 + sxs * 4;
      if (kc >= CC) kc = 0;   // OOB-safe: lands in zero-W k-slots
      char* ldn = ld0 + (buf ^ 1) * 16384;
      gl_lds16(xrow0 + kc, ldn);
      gl_lds16(xrow1 + kc, ldn + 8192);
    }
    // W B-fragments for THIS chunk, straight from L2
    bh8 w00 = wfp[(c * 2 + 0) * 512 + 0  + woff];
    bh8 w01 = wfp[(c * 2 + 0) * 512 + 64 + woff];
    bh8 w10 = wfp[(c * 2 + 1) * 512 + 0  + woff];
    bh8 w11 = wfp[(c * 2 + 1) * 512 + 64 + woff];
    const char* xa = smem + XA_OFF + buf * 16384;
#pragma unroll
    for (int ks = 0; ks < 2; ++ks) {
      bh8 af[2];
#pragma unroll
      for (int mi = 0; mi < 2; ++mi) {
        const int t = m0 + mi * 32 + l31;
        const int s0 = (ks * 4 + h5 * 2) ^ (t & 7);
        const int s1 = (ks * 4 + h5 * 2 + 1) ^ (t & 7);
        const float4 fa = *(const float4*)(xa + t * 128 + s0 * 16);
        const float4 fb = *(const float4*)(xa + t * 128 + s1 * 16);
        union { bh8 v; __hip_bfloat162 h[4]; } u;
        u.h[0] = __float22bfloat162_rn(make_float2(fa.x, fa.y));
        u.h[1] = __float22bfloat162_rn(make_float2(fa.z, fa.w));
        u.h[2] = __float22bfloat162_rn(make_float2(fb.x, fb.y));
        u.h[3] = __float22bfloat162_rn(make_float2(fb.z, fb.w));
        af[mi] = u.v;
      }
      const bh8 b0 = ks ? w10 : w00;
      const bh8 b1 = ks ? w11 : w01;
#pragma unroll
      for (int mi = 0; mi < 2; ++mi) {
        acc[mi][0] = __builtin_amdgcn_mfma_f32_32x32x16_bf16(af[mi], b0, acc[mi][0], 0, 0, 0);
        acc[mi][1] = __builtin_amdgcn_mfma_f32_32x32x16_bf16(af[mi], b1, acc[mi][1], 0, 0, 0);
      }
    }
    __syncthreads();
  }

  // epilogue: q,k -> LDS [hg][t][32B]; vT -> global ws [h][t] (packed b64 writes)
#pragma unroll
  for (int mi = 0; mi < 2; ++mi) {
    const int tb = m0 + mi * 32;
#pragma unroll
    for (int ni = 0; ni < 2; ++ni) {
      const int nn = n0 + ni * 32 + l31;
      if (nn < 160) {                      // q or k section: scalar b16 LDS writes
        const int h = (nn < 80) ? nn : nn - 80;
        char* base = smem + ((nn < 80) ? Q_OFF : K_OFF) + (h >> 4) * 4096 + (h & 15) * 2;
#pragma unroll
        for (int r = 0; r < 16; ++r) {
          const int t = tb + (r & 3) + 8 * (r >> 2) + 4 * h5;
          *(uint16_t*)(base + t * 32) = (uint16_t)f2bf1(acc[mi][ni][r]);
        }
      } else if (nn < 240) {               // v section: transposed packed global writes
        const int hh2 = nn - 160;
#pragma unroll
        for (int g = 0; g < 4; ++g) {
          const int t0 = tb + 8 * g + 4 * h5;
          *(uint2*)((char*)vtb + hh2 * 256 + t0 * 2) =
            make_uint2(packbf(acc[mi][ni][4*g],   acc[mi][ni][4*g+1]),
                       packbf(acc[mi][ni][4*g+2], acc[mi][ni][4*g+3]));
        }
      }
    }
  }
  __threadfence();   // make vT visible to this block's later reads
  __syncthreads();

  //========================= phase 2: S^T = K@Q^T, causal softmax =========================
  const int mt2 = wv & 1;                  // s-half (64 keys)
  const int tq  = (wv >> 1) * 32 + l31;    // this lane's query column
  f32x16 sac[2];
#pragma unroll
  for (int ts2 = 0; ts2 < 2; ++ts2)
#pragma unroll
    for (int r = 0; r < 16; ++r) sac[ts2][r] = 0.f;

#pragma unroll
  for (int ks = 0; ks < 5; ++ks) {         // head-dim = 80 (zeros in 75..79)
    const bh8 qf = *(const bh8*)(smem + Q_OFF + ks * 4096 + tq * 32 + h5 * 16);
#pragma unroll
    for (int ts2 = 0; ts2 < 2; ++ts2) {
      const int sr = (mt2 * 2 + ts2) * 32 + l31;
      const bh8 kf = *(const bh8*)(smem + K_OFF + ks * 4096 + sr * 32 + h5 * 16);
      sac[ts2] = __builtin_amdgcn_mfma_f32_32x32x16_bf16(kf, qf, sac[ts2], 0, 0, 0);
    }
  }

  float pvv[32];
  float vmax = -INFINITY;
  const float scl = 0.040824829046386302f;   // 600^-0.5 (reference scales by C)
#pragma unroll
  for (int ts2 = 0; ts2 < 2; ++ts2) {
    const int st = (mt2 * 2 + ts2) * 32;
#pragma unroll
    for (int r = 0; r < 16; ++r) {
      const int s = st + (r & 3) + 8 * (r >> 2) + 4 * h5;
      float v = sac[ts2][r] * scl;
      v = (s <= tq) ? v : -INFINITY;
      pvv[ts2 * 16 + r] = v;
      vmax = fmaxf(vmax, v);
    }
  }
  vmax = fmaxf(vmax, __shfl_xor(vmax, 32)); // combine half-waves -> partial over 64 keys
  float* pmb = (float*)(smem + PM_OFF);
  float* psb = (float*)(smem + PS_OFF);
  if (h5 == 0) pmb[mt2 * 128 + tq] = vmax;   // XA region is dead; safe before barrier
  __syncthreads();
  const float mrow = fmaxf(pmb[tq], pmb[128 + tq]);
  float sum = 0.f;
#pragma unroll
  for (int i = 0; i < 32; ++i) {
    const float p = bfrt(__expf(pvv[i] - mrow));  // round to bf16 so denom matches numerator
    pvv[i] = p;
    sum += p;
  }
  sum += __shfl_xor(sum, 32);
  if (h5 == 0) psb[mt2 * 128 + tq] = sum;
  // write P half-0 (s<64): only mt2==0 waves own those s values
  if (mt2 == 0) {
#pragma unroll
    for (int ts2 = 0; ts2 < 2; ++ts2) {
#pragma unroll
      for (int g = 0; g < 4; ++g) {
        const int sl = ts2 * 32 + 8 * g + 4 * h5;   // local s in [0,64)
        *(uint2*)(smem + P_OFF + pswz(tq, sl * 2)) =
          make_uint2(packbf(pvv[ts2*16+4*g],   pvv[ts2*16+4*g+1]),
                     packbf(pvv[ts2*16+4*g+2], pvv[ts2*16+4*g+3]));
      }
    }
  }
  __syncthreads();

  //========================= phase 3: O = P@V in two s-halves =========================
  const int l15   = lane & 15;
  const int q4    = lane >> 4;
  const int trow0 = wv * 16;               // wave owns 16 query rows
  f32x4 oac[5];
#pragma unroll
  for (int nt = 0; nt < 5; ++nt)
#pragma unroll
    for (int r = 0; r < 4; ++r) oac[nt][r] = 0.f;

#pragma unroll
  for (int ksl = 0; ksl < 2; ++ksl) {      // s 0..63
    const int kb = ksl * 64 + q4 * 16;
    const bh8 pf = *(const bh8*)(smem + P_OFF + pswz(trow0 + l15, kb));
#pragma unroll
    for (int nt = 0; nt < 5; ++nt) {
      const bh8 vf = *(const bh8*)((const char*)vtb + (nt * 16 + l15) * 256 + kb);
      oac[nt] = __builtin_amdgcn_mfma_f32_16x16x32_bf16(pf, vf, oac[nt], 0, 0, 0);
    }
  }
  __syncthreads();
  // write P half-1 (s in [64,128)): mt2==1 waves own those s values
  if (mt2 == 1) {
#pragma unroll
    for (int ts2 = 0; ts2 < 2; ++ts2) {
#pragma unroll
      for (int g = 0; g < 4; ++g) {
        const int sl = ts2 * 32 + 8 * g + 4 * h5;
        *(uint2*)(smem + P_OFF + pswz(tq, sl * 2)) =
          make_uint2(packbf(pvv[ts2*16+4*g],   pvv[ts2*16+4*g+1]),
                     packbf(pvv[ts2*16+4*g+2], pvv[ts2*16+4*g+3]));
      }
    }
  }
  __syncthreads();
#pragma unroll
  for (int ksl = 0; ksl < 2; ++ksl) {      // s 64..127
    const int kb = ksl * 64 + q4 * 16;
    const bh8 pf = *(const bh8*)(smem + P_OFF + pswz(trow0 + l15, kb));
#pragma unroll
    for (int nt = 0; nt < 5; ++nt) {
      const bh8 vf = *(const bh8*)((const char*)vtb + (nt * 16 + l15) * 256 + 128 + kb);
      oac[nt] = __builtin_amdgcn_mfma_f32_16x16x32_bf16(pf, vf, oac[nt], 0, 0, 0);
    }
  }

  const float* psf = (const float*)(smem + PS_OFF);
  float rinv[4];
#pragma unroll
  for (int r = 0; r < 4; ++r) {
    const int t = trow0 + q4 * 4 + r;
    rinv[r] = 1.0f / (psf[t] + psf[128 + t]);
  }
  float* ob = out + (size_t)b * (TT * HH);
#pragma unroll
  for (int nt = 0; nt < 5; ++nt) {
    const int h = nt * 16 + l15;
    if (h < HH) {
#pragma unroll
      for (int r = 0; r < 4; ++r) {
        const int t = trow0 + q4 * 4 + r;
        ob[t * HH + h] = oac[nt][r] * rinv[r];
      }
    }
  }
}

extern "C" void kernel_launch(void* const* d_in, const int* in_sizes, int n_in,
                              void* d_out, int out_size, void* d_ws, size_t ws_size,
                              hipStream_t stream) {
  (void)in_sizes; (void)n_in; (void)out_size; (void)ws_size;
  const float* x  = (const float*)d_in[0];
  const float* Wq = (const float*)d_in[1];
  const float* Wk = (const float*)d_in[2];
  const float* Wv = (const float*)d_in[3];
  uint16_t* wpack = (uint16_t*)d_ws;                          // 311,296 B
  uint16_t* vws   = (uint16_t*)((char*)d_ws + VWS_OFF);       // 10.5 MB V^T
  float* out = (float*)d_out;
  pack_w_kernel<<<38, 512, 0, stream>>>(Wq, Wk, Wv, wpack);
  head_kernel<<<512, 512, 0, stream>>>(x, wpack, vws, out);
}

// Round 6
// 250.883 us; speedup vs baseline: 1.6332x; 1.6332x over previous
//
#include <hip/hip_runtime.h>
#include <hip/hip_bf16.h>
#include <stdint.h>
#include <math.h>

#define TT 128
#define CC 600
#define HH 75

typedef __attribute__((ext_vector_type(8)))  short bh8;
typedef __attribute__((ext_vector_type(16))) float f32x16;
typedef __attribute__((ext_vector_type(4)))  float f32x4;

// ---- LDS layout (bytes), total 79872 -> 2 blocks/CU (2*79872 < 160KiB) ----
// phase 1: XA[2] f32 x-staging @0 (2*8192) [0,16384)
// phase 2+ alias: P @0 (16384)
// PM @16384 (1024), PS @17408 (1024)
// persistent: Q @18432 (20480), K @38912 (20480), VT @59392 (20480)
#define XA_OFF 0
#define P_OFF  0
#define PM_OFF 16384
#define PS_OFF 17408
#define Q_OFF  18432
#define K_OFF  38912
#define V_OFF  59392
#define LDS_BYTES 79872

__device__ __forceinline__ uint32_t f2bf1(float f) {
  uint32_t u = __float_as_uint(f);
  return (u + 0x7FFFu + ((u >> 16) & 1u)) >> 16;   // RNE f32->bf16
}
__device__ __forceinline__ uint32_t packbf(float a, float b) {
  return f2bf1(a) | (f2bf1(b) << 16);
}
__device__ __forceinline__ float bfrt(float f) {   // bf16 round-trip
  return __uint_as_float(f2bf1(f) << 16);
}
// V: 256B-stride rows, XOR-swizzle 16B-slot index by row&7
__device__ __forceinline__ int swz(int row, int bytein) {
  return row * 256 + (bytein ^ ((row & 7) << 4));
}
// P: 128B-stride rows, XOR-swizzle 16B-slot index by row&7
__device__ __forceinline__ int pswz(int row, int bytein) {
  return row * 128 + (bytein ^ ((row & 7) << 4));
}
// async global(16B) -> LDS, linear per-lane dest (wave base + lane*16)
__device__ __forceinline__ void gl_lds16(const float* g, char* l) {
  __builtin_amdgcn_global_load_lds(
      (const __attribute__((address_space(1))) unsigned int*)(const void*)g,
      (__attribute__((address_space(3))) unsigned int*)l, 16, 0, 0);
}

// ---------------- prepass: pack W as per-lane MFMA B-fragments ----------------
// fragment (cs, n, h5) = 8 bf16 of column n, k = cs*16 + h5*8 + j.
// n = sec*80 + h (0=q,1=k,2=v); zeros for h>=75, n>=240, k>=600.
__global__ void pack_w_kernel(const float* __restrict__ Wq, const float* __restrict__ Wk,
                              const float* __restrict__ Wv, uint16_t* __restrict__ wpack) {
  const int cs  = blockIdx.x;      // 0..37
  const int tid = threadIdx.x;     // 0..511
  const int n   = tid >> 1;
  const int h5  = tid & 1;
  const int sec = n / 80;
  const int h   = n - sec * 80;
  const float* W = (sec == 0) ? Wq : (sec == 1) ? Wk : (sec == 2) ? Wv : nullptr;
  const bool valid = (W != nullptr) && (h < HH);
  const int k0 = cs * 16 + h5 * 8;
  uint32_t u[4] = {0u, 0u, 0u, 0u};
  if (valid) {
#pragma unroll
    for (int j = 0; j < 8; ++j) {
      const int k = k0 + j;
      float v = (k < CC) ? W[k * HH + h] : 0.f;
      u[j >> 1] |= f2bf1(v) << ((j & 1) * 16);
    }
  }
  ((uint4*)wpack)[cs * 512 + n * 2 + h5] = make_uint4(u[0], u[1], u[2], u[3]);
}

// ---------------- main: fused qkv-projection + causal attention, one WG per batch ----------------
__global__ __launch_bounds__(512, 4) void head_kernel(
    const float* __restrict__ x, const uint16_t* __restrict__ wpack,
    float* __restrict__ out)
{
  __shared__ char smem[LDS_BYTES];
  const int tid  = threadIdx.x;
  const int b    = blockIdx.x;
  const int lane = tid & 63;
  const int wv   = tid >> 6;      // wave 0..7
  const int l31  = lane & 31;
  const int h5   = lane >> 5;

  //========================= phase 1: [128x600]@[600x240] -> q,k,v =========================
  const int m0 = (wv >> 2) * 64;  // wave tile: 64x64
  const int n0 = (wv & 3) * 64;

  f32x16 acc[2][2];
#pragma unroll
  for (int mi = 0; mi < 2; ++mi)
#pragma unroll
    for (int ni = 0; ni < 2; ++ni)
#pragma unroll
      for (int r = 0; r < 16; ++r) acc[mi][ni][r] = 0.f;

  // DMA staging: LDS tile = f32 x[t(128)][16] (64B rows), 16B slots swizzled by t&3.
  // thread tid stages LDS bytes tid*16 (row tid>>2); global source column
  // pre-swizzled so the swizzled read sees the right data (rule: swizzle
  // source + read, keep DMA dest linear).
  const int sxt  = tid >> 2;                         // 0..127
  const int sxs4 = ((tid & 3) ^ (sxt & 3)) * 4;      // pre-swizzled f32 col offset
  const float* xsrc = x + (size_t)b * (TT * CC) + (size_t)sxt * CC + sxs4;
  char* const ldd = smem + XA_OFF + tid * 16;        // = wave base + lane*16
  const bh8* wfp = (const bh8*)wpack;                // 16B W fragments in L2
  const int woff = (n0 + l31) * 2 + h5;

  { // prologue: DMA chunk 0 into buffer 0
    gl_lds16(xsrc, ldd);
    __syncthreads();
  }

  for (int c = 0; c < 38; ++c) {
    const int buf = c & 1;
    // W fragments for THIS chunk first, so the MFMA's vmcnt wait leaves the
    // DMA prefetch (issued after) still in flight.
    const bh8 w0 = wfp[c * 512 + woff];
    const bh8 w1 = wfp[c * 512 + 64 + woff];
    if (c + 1 < 38) {  // DMA next chunk into the other buffer (fire-and-forget)
      const int col = (c + 1) * 16;
      const float* src = (col + sxs4 < CC) ? (xsrc + col) : (xsrc - sxs4);
      gl_lds16(src, ldd + (buf ^ 1) * 8192);
    }
    const char* xa = smem + XA_OFF + buf * 8192;
    bh8 af[2];
#pragma unroll
    for (int mi = 0; mi < 2; ++mi) {
      const int t = m0 + mi * 32 + l31;
      const int s0 = (h5 * 2) ^ (t & 3);
      const int s1 = (h5 * 2 + 1) ^ (t & 3);
      const float4 fa = *(const float4*)(xa + t * 64 + s0 * 16);
      const float4 fb = *(const float4*)(xa + t * 64 + s1 * 16);
      union { bh8 v; __hip_bfloat162 h[4]; } u;
      u.h[0] = __float22bfloat162_rn(make_float2(fa.x, fa.y));
      u.h[1] = __float22bfloat162_rn(make_float2(fa.z, fa.w));
      u.h[2] = __float22bfloat162_rn(make_float2(fb.x, fb.y));
      u.h[3] = __float22bfloat162_rn(make_float2(fb.z, fb.w));
      af[mi] = u.v;
    }
#pragma unroll
    for (int mi = 0; mi < 2; ++mi) {
      acc[mi][0] = __builtin_amdgcn_mfma_f32_32x32x16_bf16(af[mi], w0, acc[mi][0], 0, 0, 0);
      acc[mi][1] = __builtin_amdgcn_mfma_f32_32x32x16_bf16(af[mi], w1, acc[mi][1], 0, 0, 0);
    }
    __syncthreads();
  }

  // epilogue: q,k -> LDS [hg][t][32B]; vT -> LDS [h][t] swizzled (packed b64)
#pragma unroll
  for (int mi = 0; mi < 2; ++mi) {
    const int tb = m0 + mi * 32;
#pragma unroll
    for (int ni = 0; ni < 2; ++ni) {
      const int nn = n0 + ni * 32 + l31;
      if (nn < 160) {                      // q or k section: scalar b16 LDS writes
        const int h = (nn < 80) ? nn : nn - 80;
        char* base = smem + ((nn < 80) ? Q_OFF : K_OFF) + (h >> 4) * 4096 + (h & 15) * 2;
#pragma unroll
        for (int r = 0; r < 16; ++r) {
          const int t = tb + (r & 3) + 8 * (r >> 2) + 4 * h5;
          *(uint16_t*)(base + t * 32) = (uint16_t)f2bf1(acc[mi][ni][r]);
        }
      } else if (nn < 240) {               // v section: transposed packed b64 writes
        const int hh2 = nn - 160;
#pragma unroll
        for (int g = 0; g < 4; ++g) {
          const int t0 = tb + 8 * g + 4 * h5;
          *(uint2*)(smem + V_OFF + swz(hh2, t0 * 2)) =
            make_uint2(packbf(acc[mi][ni][4*g],   acc[mi][ni][4*g+1]),
                       packbf(acc[mi][ni][4*g+2], acc[mi][ni][4*g+3]));
        }
      }
    }
  }
  __syncthreads();

  //========================= phase 2: S^T = K@Q^T, causal softmax =========================
  const int mt2 = wv & 1;                  // s-half (64 keys)
  const int tq  = (wv >> 1) * 32 + l31;    // this lane's query column
  f32x16 sac[2];
#pragma unroll
  for (int ts2 = 0; ts2 < 2; ++ts2)
#pragma unroll
    for (int r = 0; r < 16; ++r) sac[ts2][r] = 0.f;

#pragma unroll
  for (int ks = 0; ks < 5; ++ks) {         // head-dim = 80 (zeros in 75..79)
    const bh8 qf = *(const bh8*)(smem + Q_OFF + ks * 4096 + tq * 32 + h5 * 16);
#pragma unroll
    for (int ts2 = 0; ts2 < 2; ++ts2) {
      const int sr = (mt2 * 2 + ts2) * 32 + l31;
      const bh8 kf = *(const bh8*)(smem + K_OFF + ks * 4096 + sr * 32 + h5 * 16);
      sac[ts2] = __builtin_amdgcn_mfma_f32_32x32x16_bf16(kf, qf, sac[ts2], 0, 0, 0);
    }
  }

  float pvv[32];
  float vmax = -INFINITY;
  const float scl = 0.040824829046386302f;   // 600^-0.5 (reference scales by C)
#pragma unroll
  for (int ts2 = 0; ts2 < 2; ++ts2) {
    const int st = (mt2 * 2 + ts2) * 32;
#pragma unroll
    for (int r = 0; r < 16; ++r) {
      const int s = st + (r & 3) + 8 * (r >> 2) + 4 * h5;
      float v = sac[ts2][r] * scl;
      v = (s <= tq) ? v : -INFINITY;
      pvv[ts2 * 16 + r] = v;
      vmax = fmaxf(vmax, v);
    }
  }
  vmax = fmaxf(vmax, __shfl_xor(vmax, 32)); // combine half-waves -> partial over 64 keys
  float* pmb = (float*)(smem + PM_OFF);
  float* psb = (float*)(smem + PS_OFF);
  if (h5 == 0) pmb[mt2 * 128 + tq] = vmax;   // dedicated region; safe before barrier
  __syncthreads();
  const float mrow = fmaxf(pmb[tq], pmb[128 + tq]);
  float sum = 0.f;
#pragma unroll
  for (int i = 0; i < 32; ++i) {
    const float p = bfrt(__expf(pvv[i] - mrow));  // round to bf16 so denom matches numerator
    pvv[i] = p;
    sum += p;
  }
  sum += __shfl_xor(sum, 32);
  if (h5 == 0) psb[mt2 * 128 + tq] = sum;
  // write P half-0 (s<64): only mt2==0 waves own those s values (XA dead -> P alias)
  if (mt2 == 0) {
#pragma unroll
    for (int ts2 = 0; ts2 < 2; ++ts2) {
#pragma unroll
      for (int g = 0; g < 4; ++g) {
        const int sl = ts2 * 32 + 8 * g + 4 * h5;   // local s in [0,64)
        *(uint2*)(smem + P_OFF + pswz(tq, sl * 2)) =
          make_uint2(packbf(pvv[ts2*16+4*g],   pvv[ts2*16+4*g+1]),
                     packbf(pvv[ts2*16+4*g+2], pvv[ts2*16+4*g+3]));
      }
    }
  }
  __syncthreads();

  //========================= phase 3: O = P@V in two s-halves =========================
  const int l15   = lane & 15;
  const int q4    = lane >> 4;
  const int trow0 = wv * 16;               // wave owns 16 query rows
  f32x4 oac[5];
#pragma unroll
  for (int nt = 0; nt < 5; ++nt)
#pragma unroll
    for (int r = 0; r < 4; ++r) oac[nt][r] = 0.f;

#pragma unroll
  for (int ksl = 0; ksl < 2; ++ksl) {      // s 0..63
    const int kb = ksl * 64 + q4 * 16;
    const bh8 pf = *(const bh8*)(smem + P_OFF + pswz(trow0 + l15, kb));
#pragma unroll
    for (int nt = 0; nt < 5; ++nt) {
      const bh8 vf = *(const bh8*)(smem + V_OFF + swz(nt * 16 + l15, kb));
      oac[nt] = __builtin_amdgcn_mfma_f32_16x16x32_bf16(pf, vf, oac[nt], 0, 0, 0);
    }
  }
  __syncthreads();
  // write P half-1 (s in [64,128)): mt2==1 waves own those s values
  if (mt2 == 1) {
#pragma unroll
    for (int ts2 = 0; ts2 < 2; ++ts2) {
#pragma unroll
      for (int g = 0; g < 4; ++g) {
        const int sl = ts2 * 32 + 8 * g + 4 * h5;
        *(uint2*)(smem + P_OFF + pswz(tq, sl * 2)) =
          make_uint2(packbf(pvv[ts2*16+4*g],   pvv[ts2*16+4*g+1]),
                     packbf(pvv[ts2*16+4*g+2], pvv[ts2*16+4*g+3]));
      }
    }
  }
  __syncthreads();
#pragma unroll
  for (int ksl = 0; ksl < 2; ++ksl) {      // s 64..127
    const int kb = ksl * 64 + q4 * 16;
    const bh8 pf = *(const bh8*)(smem + P_OFF + pswz(trow0 + l15, kb));
#pragma unroll
    for (int nt = 0; nt < 5; ++nt) {
      const bh8 vf = *(const bh8*)(smem + V_OFF + swz(nt * 16 + l15, 128 + kb));
      oac[nt] = __builtin_amdgcn_mfma_f32_16x16x32_bf16(pf, vf, oac[nt], 0, 0, 0);
    }
  }

  const float* psf = (const float*)(smem + PS_OFF);
  float rinv[4];
#pragma unroll
  for (int r = 0; r < 4; ++r) {
    const int t = trow0 + q4 * 4 + r;
    rinv[r] = 1.0f / (psf[t] + psf[128 + t]);
  }
  float* ob = out + (size_t)b * (TT * HH);
#pragma unroll
  for (int nt = 0; nt < 5; ++nt) {
    const int h = nt * 16 + l15;
    if (h < HH) {
#pragma unroll
      for (int r = 0; r < 4; ++r) {
        const int t = trow0 + q4 * 4 + r;
        ob[t * HH + h] = oac[nt][r] * rinv[r];
      }
    }
  }
}

extern "C" void kernel_launch(void* const* d_in, const int* in_sizes, int n_in,
                              void* d_out, int out_size, void* d_ws, size_t ws_size,
                              hipStream_t stream) {
  (void)in_sizes; (void)n_in; (void)out_size; (void)ws_size;
  const float* x  = (const float*)d_in[0];
  const float* Wq = (const float*)d_in[1];
  const float* Wk = (const float*)d_in[2];
  const float* Wv = (const float*)d_in[3];
  uint16_t* wpack = (uint16_t*)d_ws;       // 38*256*16*2 = 311,296 B
  float* out = (float*)d_out;
  pack_w_kernel<<<38, 512, 0, stream>>>(Wq, Wk, Wv, wpack);
  head_kernel<<<512, 512, 0, stream>>>(x, wpack, out);
}